// Round 14
// baseline (144.042 us; speedup 1.0000x reference)
//
#include <hip/hip_runtime.h>
#include <math.h>

constexpr int C = 20;   // classes
constexpr int M = 32;   // max GT per image

// d_ws layout: part[(b*nblk + bx)*4 + {0,1,2}] = {cls_sum, reg_sum, num_pos}
// per block. Plain stores — NO atomics (R12/R13 lesson: device-scope atomicAdd
// to 2 cache lines serializes at ~28 cyc each; 11K atomics == 135 us).
__global__ __launch_bounds__(256) void focal_main(
    const float* __restrict__ cls,   // [B,A,C]
    const float* __restrict__ reg,   // [B,A,4]
    const float* __restrict__ anc,   // [A,4]
    const float* __restrict__ ann,   // [B,M,5]
    float* __restrict__ part,
    int A)
{
    __shared__ float4 s_gbox[M];   // {x1,y1,x2,y2}; invalid GT -> zero box (iou=0)
    __shared__ float  s_garea[M];
    __shared__ int    s_glbl[M];
    __shared__ float  s_red[4 * 3];

    const int b   = blockIdx.y;
    const int tid = threadIdx.x;

    // ---- stage annotations (validity folded: 2 LDS reads/GT in IoU loop
    //      instead of 6 scalar ds_read_u32 — R13's loop issued 192 LDS ops) ----
    if (tid < M) {
        const float* ap = ann + (size_t)b * M * 5 + (size_t)tid * 5;
        float x1 = ap[0], y1 = ap[1], x2 = ap[2], y2 = ap[3];
        const float lb = ap[4];
        s_glbl[tid] = (int)lb;
        if (lb == -1.0f) { x1 = 0.f; y1 = 0.f; x2 = 0.f; y2 = 0.f; }
        s_gbox[tid]  = make_float4(x1, y1, x2, y2);
        s_garea[tid] = (x2 - x1) * (y2 - y1);
    }
    __syncthreads();

    const int a = blockIdx.x * 256 + tid;

    float clsSum = 0.f, regSum = 0.f, posf = 0.f;

    if (a < A) {
        const float4 av = *(const float4*)(anc + (size_t)a * 4);
        const float aw  = av.z - av.x;
        const float ah  = av.w - av.y;
        const float acx = av.x + 0.5f * aw;
        const float acy = av.y + 0.5f * ah;
        const float area_a = aw * ah;

        // ---- IoU max / argmax over M GT (b128 + b32 broadcast reads) ----
        float bv = -1.0f;
        int   bi = 0;
        #pragma unroll
        for (int j = 0; j < M; ++j) {
            const float4 g  = s_gbox[j];
            const float  ab = s_garea[j];
            const float iw = fmaxf(fminf(av.z, g.z) - fmaxf(av.x, g.x), 0.f);
            const float ih = fmaxf(fminf(av.w, g.w) - fmaxf(av.y, g.y), 0.f);
            const float inter = iw * ih;
            const float ua = fmaxf(area_a + ab - inter, 1e-8f);
            const float iou = __fdividef(inter, ua);
            if (iou > bv) { bv = iou; bi = j; }   // first-occurrence argmax
        }

        const bool pos    = bv >= 0.5f;
        const bool ignore = (bv >= 0.4f) && !pos;
        const int  lbl    = s_glbl[bi];           // valid whenever pos

        // ---- classification focal loss (branchless; mask ignore at end) ----
        const float* cp = cls + ((size_t)b * A + a) * C;
        const float4 c0 = *(const float4*)(cp + 0);
        const float4 c1 = *(const float4*)(cp + 4);
        const float4 c2 = *(const float4*)(cp + 8);
        const float4 c3 = *(const float4*)(cp + 12);
        const float4 c4 = *(const float4*)(cp + 16);
        float pv[C];
        pv[0]=c0.x;  pv[1]=c0.y;  pv[2]=c0.z;  pv[3]=c0.w;
        pv[4]=c1.x;  pv[5]=c1.y;  pv[6]=c1.z;  pv[7]=c1.w;
        pv[8]=c2.x;  pv[9]=c2.y;  pv[10]=c2.z; pv[11]=c2.w;
        pv[12]=c3.x; pv[13]=c3.y; pv[14]=c3.z; pv[15]=c3.w;
        pv[16]=c4.x; pv[17]=c4.y; pv[18]=c4.z; pv[19]=c4.w;

        #pragma unroll
        for (int c = 0; c < C; ++c) {
            const float p  = fminf(fmaxf(pv[c], 1e-8f), 1.0f - 1e-8f);
            const float q  = 1.0f - p;
            const bool  t1 = pos && (c == lbl);
            const float pe = t1 ? q : p;           // focal-modulation prob
            const float po = t1 ? p : q;           // prob inside the log
            const float w  = t1 ? 0.2f : 0.8f;
            // pe^1.5 == pe*sqrt(pe) exactly (gamma=1.5); v_sqrt_f32 is 1-ulp
            clsSum += w * pe * __builtin_amdgcn_sqrtf(pe) * (-__logf(po));
        }
        clsSum = ignore ? 0.f : clsSum;

        // ---- regression smooth-L1 (positives only) ----
        if (pos) {
            posf = 1.0f;
            const float4 g = s_gbox[bi];
            const float gwr = g.z - g.x, ghr = g.w - g.y;
            const float gcx = g.x + 0.5f * gwr, gcy = g.y + 0.5f * ghr;
            const float gw = fmaxf(gwr, 1.f), gh = fmaxf(ghr, 1.f);
            float rt[4];
            rt[0] = ((gcx - acx) / aw) / 0.1f;
            rt[1] = ((gcy - acy) / ah) / 0.1f;
            rt[2] = __logf(gw / aw) / 0.2f;
            rt[3] = __logf(gh / ah) / 0.2f;
            const float4 rv = *(const float4*)(reg + ((size_t)b * A + a) * 4);
            const float rr[4] = {rv.x, rv.y, rv.z, rv.w};
            #pragma unroll
            for (int u = 0; u < 4; ++u) {
                const float d = fabsf(rt[u] - rr[u]);
                regSum += (d <= (float)(1.0 / 9.0)) ? (4.5f * d * d)
                                                    : (d - (float)(0.5 / 9.0));
            }
        }
    }

    // ---- block reduce: wave shuffle -> cross-wave LDS -> ONE plain store ----
    #pragma unroll
    for (int off = 32; off > 0; off >>= 1) {
        clsSum += __shfl_down(clsSum, off, 64);
        regSum += __shfl_down(regSum, off, 64);
        posf   += __shfl_down(posf,   off, 64);
    }
    const int wave = tid >> 6;
    const int lane = tid & 63;
    if (lane == 0) {
        s_red[wave*3+0] = clsSum;
        s_red[wave*3+1] = regSum;
        s_red[wave*3+2] = posf;
    }
    __syncthreads();
    if (tid == 0) {
        float cs = 0.f, rs = 0.f, ps = 0.f;
        #pragma unroll
        for (int w2 = 0; w2 < 4; ++w2) {
            cs += s_red[w2*3+0];
            rs += s_red[w2*3+1];
            ps += s_red[w2*3+2];
        }
        const size_t slot = ((size_t)b * gridDim.x + blockIdx.x) * 4;
        *(float4*)(part + slot) = make_float4(cs, rs, ps, 0.f);
    }
}

// Tree-reduce the B x nblk partial triplets + final normalization.
// 1024 threads: 128 threads per image (B=8).
__global__ __launch_bounds__(1024) void focal_final(
    const float* __restrict__ part,
    const float* __restrict__ ann,
    float* __restrict__ out, int B, int nblk)
{
    __shared__ float s_sum[8][2][3];   // [image][wave-in-group][{cls,reg,pos}]
    __shared__ float s_f[256];
    __shared__ float s_c[8], s_r[8];

    const int tid = threadIdx.x;
    const int g   = tid >> 7;          // image 0..7
    const int i   = tid & 127;

    float cs = 0.f, rs = 0.f, ps = 0.f;
    if (g < B) {
        for (int bx = i; bx < nblk; bx += 128) {
            const float4 v = *(const float4*)(part + ((size_t)g * nblk + bx) * 4);
            cs += v.x; rs += v.y; ps += v.z;
        }
    }
    #pragma unroll
    for (int off = 32; off > 0; off >>= 1) {
        cs += __shfl_down(cs, off, 64);
        rs += __shfl_down(rs, off, 64);
        ps += __shfl_down(ps, off, 64);
    }
    const int lane = tid & 63;
    const int wv   = (tid >> 6) & 1;   // wave within the 128-thread group
    if (lane == 0 && g < 8) {
        s_sum[g][wv][0] = cs; s_sum[g][wv][1] = rs; s_sum[g][wv][2] = ps;
    }

    // GT validity flags in parallel (B*M = 256)
    if (tid < 256) {
        float f = 0.f;
        if (tid < B * M) {
            const int bb = tid >> 5, j = tid & 31;
            f = (ann[(size_t)bb * M * 5 + (size_t)j * 5 + 4] != -1.0f) ? 1.f : 0.f;
        }
        s_f[tid] = f;
    }
    __syncthreads();

    if (tid < B) {
        const float S  = s_sum[tid][0][0] + s_sum[tid][1][0];
        const float R  = s_sum[tid][0][1] + s_sum[tid][1][1];
        const float np = s_sum[tid][0][2] + s_sum[tid][1][2];
        float nv = 0.f;
        #pragma unroll
        for (int j = 0; j < M; ++j) nv += s_f[tid * M + j];
        float cl = S / fmaxf(np, 1.f);
        float rl = (np > 0.f) ? R / fmaxf(4.f * np, 1.f) : 0.f;
        if (nv == 0.f) { cl = 0.f; rl = 0.f; }
        s_c[tid] = cl; s_r[tid] = rl;
    }
    __syncthreads();

    if (tid == 0) {
        float ca = 0.f, ra = 0.f;
        for (int b2 = 0; b2 < B; ++b2) { ca += s_c[b2]; ra += s_r[b2]; }
        out[0] = ca / (float)B;
        out[1] = ra / (float)B;
    }
}

extern "C" void kernel_launch(void* const* d_in, const int* in_sizes, int n_in,
                              void* d_out, int out_size, void* d_ws, size_t ws_size,
                              hipStream_t stream) {
    const float* cls = (const float*)d_in[0];   // [B,A,C]
    const float* reg = (const float*)d_in[1];   // [B,A,4]
    const float* anc = (const float*)d_in[2];   // [1,A,4]
    const float* ann = (const float*)d_in[3];   // [B,M,5]
    const int A = in_sizes[2] / 4;
    const int B = in_sizes[3] / (M * 5);
    const int nblk = (A + 255) / 256;

    float* part = (float*)d_ws;   // B*nblk*4 floats (~60 KB); every slot is
                                  // written by focal_main, so no memset needed.

    dim3 grid(nblk, B);
    focal_main<<<grid, dim3(256), 0, stream>>>(cls, reg, anc, ann, part, A);
    focal_final<<<1, dim3(1024), 0, stream>>>(part, ann, (float*)d_out, B, nblk);
}

// Round 15
// 143.077 us; speedup vs baseline: 1.0067x; 1.0067x over previous
//
#include <hip/hip_runtime.h>
#include <math.h>

constexpr int C = 20;   // classes
constexpr int M = 32;   // max GT per image

// d_ws layout: part[(b*nblk + bx)*4 + {0,1,2}] = {cls_sum, reg_sum, num_pos}
// per block. Plain stores — NO atomics (R12/R13 lesson: device-scope atomicAdd
// to 2 cache lines serializes at ~28 cyc each; 11K atomics == 135 us).
__global__ __launch_bounds__(256) void focal_main(
    const float* __restrict__ cls,   // [B,A,C]
    const float* __restrict__ reg,   // [B,A,4]
    const float* __restrict__ anc,   // [A,4]
    const float* __restrict__ ann,   // [B,M,5]
    float* __restrict__ part,
    int A)
{
    __shared__ float4 s_gbox[M];   // {x1,y1,x2,y2}; invalid GT -> zero box (iou=0)
    __shared__ float  s_garea[M];
    __shared__ int    s_glbl[M];
    __shared__ float  s_red[4 * 3];

    const int b   = blockIdx.y;
    const int tid = threadIdx.x;

    // ---- stage annotations (validity folded: 2 LDS reads/GT in IoU loop) ----
    if (tid < M) {
        const float* ap = ann + (size_t)b * M * 5 + (size_t)tid * 5;
        float x1 = ap[0], y1 = ap[1], x2 = ap[2], y2 = ap[3];
        const float lb = ap[4];
        s_glbl[tid] = (int)lb;
        if (lb == -1.0f) { x1 = 0.f; y1 = 0.f; x2 = 0.f; y2 = 0.f; }
        s_gbox[tid]  = make_float4(x1, y1, x2, y2);
        s_garea[tid] = (x2 - x1) * (y2 - y1);
    }
    __syncthreads();

    const int a = blockIdx.x * 256 + tid;

    float clsSum = 0.f, regSum = 0.f, posf = 0.f;

    if (a < A) {
        const float4 av = *(const float4*)(anc + (size_t)a * 4);
        const float aw  = av.z - av.x;
        const float ah  = av.w - av.y;
        const float acx = av.x + 0.5f * aw;
        const float acy = av.y + 0.5f * ah;
        const float area_a = aw * ah;

        // ---- IoU max / argmax over M GT (b128 + b32 broadcast reads) ----
        float bv = -1.0f;
        int   bi = 0;
        #pragma unroll
        for (int j = 0; j < M; ++j) {
            const float4 g  = s_gbox[j];
            const float  ab = s_garea[j];
            const float iw = fmaxf(fminf(av.z, g.z) - fmaxf(av.x, g.x), 0.f);
            const float ih = fmaxf(fminf(av.w, g.w) - fmaxf(av.y, g.y), 0.f);
            const float inter = iw * ih;
            const float ua = fmaxf(area_a + ab - inter, 1e-8f);
            const float iou = __fdividef(inter, ua);
            if (iou > bv) { bv = iou; bi = j; }   // first-occurrence argmax
        }

        const bool pos    = bv >= 0.5f;
        const bool ignore = (bv >= 0.4f) && !pos;
        const int  lbl    = s_glbl[bi];           // in [0,19] whenever pos

        // ---- classification focal loss: negative-form sum + pos correction.
        //      Streaming k-loop (one float4 at a time) keeps VGPR low (R14
        //      lesson: pv[20] batch -> VGPR 80, occupancy 25%, net loss). ----
        if (!ignore) {
            const float* cp = cls + ((size_t)b * A + a) * C;
            float sum = 0.f;
            float p_t = 0.5f;                     // label-class prob (pos only)
            #pragma unroll
            for (int k = 0; k < C / 4; ++k) {
                const float4 v = *(const float4*)(cp + k * 4);
                const float pv4[4] = {v.x, v.y, v.z, v.w};
                #pragma unroll
                for (int u = 0; u < 4; ++u) {
                    const int c = k * 4 + u;
                    const float p = fminf(fmaxf(pv4[u], 1e-8f), 1.0f - 1e-8f);
                    // unweighted negative term: p^1.5 * (-log(1-p)); ^1.5 exact
                    sum += p * __builtin_amdgcn_sqrtf(p) * (-__logf(1.0f - p));
                    p_t = (c == lbl) ? p : p_t;   // one cndmask per class
                }
            }
            sum *= 0.8f;
            if (pos) {                            // swap in the label-class term
                const float q = 1.0f - p_t;
                sum -= 0.8f * p_t * __builtin_amdgcn_sqrtf(p_t) * (-__logf(q));
                sum += 0.2f * q   * __builtin_amdgcn_sqrtf(q)   * (-__logf(p_t));
            }
            clsSum = sum;
        }

        // ---- regression smooth-L1 (positives only) ----
        if (pos) {
            posf = 1.0f;
            const float4 g = s_gbox[bi];
            const float gwr = g.z - g.x, ghr = g.w - g.y;
            const float gcx = g.x + 0.5f * gwr, gcy = g.y + 0.5f * ghr;
            const float gw = fmaxf(gwr, 1.f), gh = fmaxf(ghr, 1.f);
            float rt[4];
            rt[0] = ((gcx - acx) / aw) / 0.1f;
            rt[1] = ((gcy - acy) / ah) / 0.1f;
            rt[2] = __logf(gw / aw) / 0.2f;
            rt[3] = __logf(gh / ah) / 0.2f;
            const float4 rv = *(const float4*)(reg + ((size_t)b * A + a) * 4);
            const float rr[4] = {rv.x, rv.y, rv.z, rv.w};
            #pragma unroll
            for (int u = 0; u < 4; ++u) {
                const float d = fabsf(rt[u] - rr[u]);
                regSum += (d <= (float)(1.0 / 9.0)) ? (4.5f * d * d)
                                                    : (d - (float)(0.5 / 9.0));
            }
        }
    }

    // ---- block reduce: wave shuffle -> cross-wave LDS -> ONE plain store ----
    #pragma unroll
    for (int off = 32; off > 0; off >>= 1) {
        clsSum += __shfl_down(clsSum, off, 64);
        regSum += __shfl_down(regSum, off, 64);
        posf   += __shfl_down(posf,   off, 64);
    }
    const int wave = tid >> 6;
    const int lane = tid & 63;
    if (lane == 0) {
        s_red[wave*3+0] = clsSum;
        s_red[wave*3+1] = regSum;
        s_red[wave*3+2] = posf;
    }
    __syncthreads();
    if (tid == 0) {
        float cs = 0.f, rs = 0.f, ps = 0.f;
        #pragma unroll
        for (int w2 = 0; w2 < 4; ++w2) {
            cs += s_red[w2*3+0];
            rs += s_red[w2*3+1];
            ps += s_red[w2*3+2];
        }
        const size_t slot = ((size_t)b * gridDim.x + blockIdx.x) * 4;
        *(float4*)(part + slot) = make_float4(cs, rs, ps, 0.f);
    }
}

// Tree-reduce the B x nblk partial triplets + final normalization.
// 1024 threads: 128 threads per image (B=8).
__global__ __launch_bounds__(1024) void focal_final(
    const float* __restrict__ part,
    const float* __restrict__ ann,
    float* __restrict__ out, int B, int nblk)
{
    __shared__ float s_sum[8][2][3];   // [image][wave-in-group][{cls,reg,pos}]
    __shared__ float s_f[256];
    __shared__ float s_c[8], s_r[8];

    const int tid = threadIdx.x;
    const int g   = tid >> 7;          // image 0..7
    const int i   = tid & 127;

    float cs = 0.f, rs = 0.f, ps = 0.f;
    if (g < B) {
        for (int bx = i; bx < nblk; bx += 128) {
            const float4 v = *(const float4*)(part + ((size_t)g * nblk + bx) * 4);
            cs += v.x; rs += v.y; ps += v.z;
        }
    }
    #pragma unroll
    for (int off = 32; off > 0; off >>= 1) {
        cs += __shfl_down(cs, off, 64);
        rs += __shfl_down(rs, off, 64);
        ps += __shfl_down(ps, off, 64);
    }
    const int lane = tid & 63;
    const int wv   = (tid >> 6) & 1;   // wave within the 128-thread group
    if (lane == 0 && g < 8) {
        s_sum[g][wv][0] = cs; s_sum[g][wv][1] = rs; s_sum[g][wv][2] = ps;
    }

    // GT validity flags in parallel (B*M = 256)
    if (tid < 256) {
        float f = 0.f;
        if (tid < B * M) {
            const int bb = tid >> 5, j = tid & 31;
            f = (ann[(size_t)bb * M * 5 + (size_t)j * 5 + 4] != -1.0f) ? 1.f : 0.f;
        }
        s_f[tid] = f;
    }
    __syncthreads();

    if (tid < B) {
        const float S  = s_sum[tid][0][0] + s_sum[tid][1][0];
        const float R  = s_sum[tid][0][1] + s_sum[tid][1][1];
        const float np = s_sum[tid][0][2] + s_sum[tid][1][2];
        float nv = 0.f;
        #pragma unroll
        for (int j = 0; j < M; ++j) nv += s_f[tid * M + j];
        float cl = S / fmaxf(np, 1.f);
        float rl = (np > 0.f) ? R / fmaxf(4.f * np, 1.f) : 0.f;
        if (nv == 0.f) { cl = 0.f; rl = 0.f; }
        s_c[tid] = cl; s_r[tid] = rl;
    }
    __syncthreads();

    if (tid == 0) {
        float ca = 0.f, ra = 0.f;
        for (int b2 = 0; b2 < B; ++b2) { ca += s_c[b2]; ra += s_r[b2]; }
        out[0] = ca / (float)B;
        out[1] = ra / (float)B;
    }
}

extern "C" void kernel_launch(void* const* d_in, const int* in_sizes, int n_in,
                              void* d_out, int out_size, void* d_ws, size_t ws_size,
                              hipStream_t stream) {
    const float* cls = (const float*)d_in[0];   // [B,A,C]
    const float* reg = (const float*)d_in[1];   // [B,A,4]
    const float* anc = (const float*)d_in[2];   // [1,A,4]
    const float* ann = (const float*)d_in[3];   // [B,M,5]
    const int A = in_sizes[2] / 4;
    const int B = in_sizes[3] / (M * 5);
    const int nblk = (A + 255) / 256;

    float* part = (float*)d_ws;   // B*nblk*4 floats (~60 KB); every slot is
                                  // written by focal_main, so no memset needed.

    dim3 grid(nblk, B);
    focal_main<<<grid, dim3(256), 0, stream>>>(cls, reg, anc, ann, part, A);
    focal_final<<<1, dim3(1024), 0, stream>>>(part, ann, (float*)d_out, B, nblk);
}

// Round 16
// 129.091 us; speedup vs baseline: 1.1158x; 1.1083x over previous
//
#include <hip/hip_runtime.h>
#include <math.h>

constexpr int C = 20;   // classes
constexpr int M = 32;   // max GT per image
#define LN2F 0.69314718055994530942f

// d_ws layout: part[(b*nblk + bx)*4 + {0,1,2}] = {cls_sum, reg_sum, num_pos}
// per block. Plain stores — NO atomics (R12/R13 lesson: device-scope atomicAdd
// to 2 cache lines serializes at ~28 cyc each; 11K atomics == 135 us).
__global__ __launch_bounds__(256) void focal_main(
    const float* __restrict__ cls,   // [B,A,C]
    const float* __restrict__ reg,   // [B,A,4]
    const float* __restrict__ anc,   // [A,4]
    const float* __restrict__ ann,   // [B,M,5]
    float* __restrict__ part,
    int A)
{
    __shared__ float4 s_gbox[M];   // {x1,y1,x2,y2}; invalid GT -> zero box (iou=0)
    __shared__ float  s_garea[M];
    __shared__ int    s_glbl[M];
    __shared__ float  s_red[4 * 3];

    const int b   = blockIdx.y;
    const int tid = threadIdx.x;

    // ---- stage annotations (validity folded: 2 LDS reads/GT in IoU loop) ----
    if (tid < M) {
        const float* ap = ann + (size_t)b * M * 5 + (size_t)tid * 5;
        float x1 = ap[0], y1 = ap[1], x2 = ap[2], y2 = ap[3];
        const float lb = ap[4];
        s_glbl[tid] = (int)lb;
        if (lb == -1.0f) { x1 = 0.f; y1 = 0.f; x2 = 0.f; y2 = 0.f; }
        s_gbox[tid]  = make_float4(x1, y1, x2, y2);
        s_garea[tid] = (x2 - x1) * (y2 - y1);
    }
    __syncthreads();

    const int a = blockIdx.x * 256 + tid;

    float clsSum = 0.f, regSum = 0.f, posf = 0.f;

    if (a < A) {
        const float4 av = *(const float4*)(anc + (size_t)a * 4);
        const float aw  = av.z - av.x;
        const float ah  = av.w - av.y;
        const float acx = av.x + 0.5f * aw;
        const float acy = av.y + 0.5f * ah;
        const float area_a = aw * ah;

        // ---- IoU argmax, division-free: best kept as fraction (n_b/d_b).
        //      n_j*d_b > n_b*d_j replaces rcp+mul per GT (one rcp per anchor).
        //      unroll 8: full 32-unroll batched ds_reads -> VGPR 80, occ 25%. ----
        float n_b = -1.0f, d_b = 1.0f;
        int   bi = 0;
        #pragma unroll 8
        for (int j = 0; j < M; ++j) {
            const float4 g  = s_gbox[j];
            const float  ab = s_garea[j];
            const float iw = fmaxf(fminf(av.z, g.z) - fmaxf(av.x, g.x), 0.f);
            const float ih = fmaxf(fminf(av.w, g.w) - fmaxf(av.y, g.y), 0.f);
            const float inter = iw * ih;
            const float ua = fmaxf(area_a + ab - inter, 1e-8f);
            if (inter * d_b > n_b * ua) { n_b = inter; d_b = ua; bi = j; }
        }
        const float bv = n_b * __frcp_rn(d_b);    // value only for thresholds
        const bool pos    = bv >= 0.5f;
        const bool ignore = (bv >= 0.4f) && !pos;
        const int  lbl    = s_glbl[bi];           // in [0,19] whenever pos

        // ---- classification focal loss: negative-form sum in log2 space.
        //      cls = 0.8*ln2 * sum(p^1.5 * -log2(1-p)) (+ pos correction). ----
        if (!ignore) {
            const float* cp = cls + ((size_t)b * A + a) * C;
            float sum = 0.f;                      // in log2 units
            float p_t = 0.5f;                     // label-class prob (pos only)
            #pragma unroll
            for (int k = 0; k < C / 4; ++k) {
                const float4 v = *(const float4*)(cp + k * 4);
                const float pv4[4] = {v.x, v.y, v.z, v.w};
                #pragma unroll
                for (int u = 0; u < 4; ++u) {
                    const int c = k * 4 + u;
                    const float p = fminf(fmaxf(pv4[u], 1e-8f), 1.0f - 1e-8f);
                    sum += p * __builtin_amdgcn_sqrtf(p) * (-__log2f(1.0f - p));
                    p_t = (c == lbl) ? p : p_t;   // one cndmask per class
                }
            }
            sum *= 0.8f;
            if (pos) {                            // swap in the label-class term
                const float q = 1.0f - p_t;
                sum -= 0.8f * p_t * __builtin_amdgcn_sqrtf(p_t) * (-__log2f(q));
                sum += 0.2f * q   * __builtin_amdgcn_sqrtf(q)   * (-__log2f(p_t));
            }
            clsSum = sum * LN2F;
        }

        // ---- regression smooth-L1 (positives only) ----
        if (pos) {
            posf = 1.0f;
            const float4 g = s_gbox[bi];
            const float gwr = g.z - g.x, ghr = g.w - g.y;
            const float gcx = g.x + 0.5f * gwr, gcy = g.y + 0.5f * ghr;
            const float gw = fmaxf(gwr, 1.f), gh = fmaxf(ghr, 1.f);
            float rt[4];
            rt[0] = ((gcx - acx) / aw) / 0.1f;
            rt[1] = ((gcy - acy) / ah) / 0.1f;
            rt[2] = __logf(gw / aw) / 0.2f;
            rt[3] = __logf(gh / ah) / 0.2f;
            const float4 rv = *(const float4*)(reg + ((size_t)b * A + a) * 4);
            const float rr[4] = {rv.x, rv.y, rv.z, rv.w};
            #pragma unroll
            for (int u = 0; u < 4; ++u) {
                const float d = fabsf(rt[u] - rr[u]);
                regSum += (d <= (float)(1.0 / 9.0)) ? (4.5f * d * d)
                                                    : (d - (float)(0.5 / 9.0));
            }
        }
    }

    // ---- block reduce: wave shuffle -> cross-wave LDS -> ONE plain store ----
    #pragma unroll
    for (int off = 32; off > 0; off >>= 1) {
        clsSum += __shfl_down(clsSum, off, 64);
        regSum += __shfl_down(regSum, off, 64);
        posf   += __shfl_down(posf,   off, 64);
    }
    const int wave = tid >> 6;
    const int lane = tid & 63;
    if (lane == 0) {
        s_red[wave*3+0] = clsSum;
        s_red[wave*3+1] = regSum;
        s_red[wave*3+2] = posf;
    }
    __syncthreads();
    if (tid == 0) {
        float cs = 0.f, rs = 0.f, ps = 0.f;
        #pragma unroll
        for (int w2 = 0; w2 < 4; ++w2) {
            cs += s_red[w2*3+0];
            rs += s_red[w2*3+1];
            ps += s_red[w2*3+2];
        }
        const size_t slot = ((size_t)b * gridDim.x + blockIdx.x) * 4;
        *(float4*)(part + slot) = make_float4(cs, rs, ps, 0.f);
    }
}

// Tree-reduce the B x nblk partial triplets + final normalization.
// 1024 threads: 128 threads per image (B=8).
__global__ __launch_bounds__(1024) void focal_final(
    const float* __restrict__ part,
    const float* __restrict__ ann,
    float* __restrict__ out, int B, int nblk)
{
    __shared__ float s_sum[8][2][3];   // [image][wave-in-group][{cls,reg,pos}]
    __shared__ float s_f[256];
    __shared__ float s_c[8], s_r[8];

    const int tid = threadIdx.x;
    const int g   = tid >> 7;          // image 0..7
    const int i   = tid & 127;

    float cs = 0.f, rs = 0.f, ps = 0.f;
    if (g < B) {
        for (int bx = i; bx < nblk; bx += 128) {
            const float4 v = *(const float4*)(part + ((size_t)g * nblk + bx) * 4);
            cs += v.x; rs += v.y; ps += v.z;
        }
    }
    #pragma unroll
    for (int off = 32; off > 0; off >>= 1) {
        cs += __shfl_down(cs, off, 64);
        rs += __shfl_down(rs, off, 64);
        ps += __shfl_down(ps, off, 64);
    }
    const int lane = tid & 63;
    const int wv   = (tid >> 6) & 1;   // wave within the 128-thread group
    if (lane == 0 && g < 8) {
        s_sum[g][wv][0] = cs; s_sum[g][wv][1] = rs; s_sum[g][wv][2] = ps;
    }

    // GT validity flags in parallel (B*M = 256)
    if (tid < 256) {
        float f = 0.f;
        if (tid < B * M) {
            const int bb = tid >> 5, j = tid & 31;
            f = (ann[(size_t)bb * M * 5 + (size_t)j * 5 + 4] != -1.0f) ? 1.f : 0.f;
        }
        s_f[tid] = f;
    }
    __syncthreads();

    if (tid < B) {
        const float S  = s_sum[tid][0][0] + s_sum[tid][1][0];
        const float R  = s_sum[tid][0][1] + s_sum[tid][1][1];
        const float np = s_sum[tid][0][2] + s_sum[tid][1][2];
        float nv = 0.f;
        #pragma unroll
        for (int j = 0; j < M; ++j) nv += s_f[tid * M + j];
        float cl = S / fmaxf(np, 1.f);
        float rl = (np > 0.f) ? R / fmaxf(4.f * np, 1.f) : 0.f;
        if (nv == 0.f) { cl = 0.f; rl = 0.f; }
        s_c[tid] = cl; s_r[tid] = rl;
    }
    __syncthreads();

    if (tid == 0) {
        float ca = 0.f, ra = 0.f;
        for (int b2 = 0; b2 < B; ++b2) { ca += s_c[b2]; ra += s_r[b2]; }
        out[0] = ca / (float)B;
        out[1] = ra / (float)B;
    }
}

extern "C" void kernel_launch(void* const* d_in, const int* in_sizes, int n_in,
                              void* d_out, int out_size, void* d_ws, size_t ws_size,
                              hipStream_t stream) {
    const float* cls = (const float*)d_in[0];   // [B,A,C]
    const float* reg = (const float*)d_in[1];   // [B,A,4]
    const float* anc = (const float*)d_in[2];   // [1,A,4]
    const float* ann = (const float*)d_in[3];   // [B,M,5]
    const int A = in_sizes[2] / 4;
    const int B = in_sizes[3] / (M * 5);
    const int nblk = (A + 255) / 256;

    float* part = (float*)d_ws;   // B*nblk*4 floats (~60 KB); every slot is
                                  // written by focal_main, so no memset needed.

    dim3 grid(nblk, B);
    focal_main<<<grid, dim3(256), 0, stream>>>(cls, reg, anc, ann, part, A);
    focal_final<<<1, dim3(1024), 0, stream>>>(part, ann, (float*)d_out, B, nblk);
}